// Round 15
// baseline (385.772 us; speedup 1.0000x reference)
//
#include <hip/hip_runtime.h>
#include <hip/hip_bf16.h>
#include <stdint.h>

#define NND 12000
#define DM  256
#define KNN 16
#define NB  4096          // x-buckets
#define BW  0.00390625f   // bucket width = 1/256 over [-8, 8)
#define RW  16            // fixed-window rounds (16*64 = 1024 candidates)
#define NWELEM 360448     // total weight elements converted to bf16 hi/lo
#define EBLK 768          // encoder blocks first (==0 mod 8: XCD swizzle intact)

// Opaque register barrier: prevents FMA contraction (r9: made knn bit-match numpy
// -> absmax 0.0. DO NOT REMOVE from knn path).
#define FPBAR(x) asm volatile("" : "+v"(x))

typedef unsigned long long u64;
typedef __attribute__((ext_vector_type(8))) short bf8_t;   // 8 bf16 (4 VGPRs)
typedef __attribute__((ext_vector_type(4))) float f4_t;

__device__ __forceinline__ float geluf(float x){ return 0.5f*x*(1.0f + erff(x*0.70710678118654752f)); }
__device__ __forceinline__ int bucketof(float x){
  int b = (int)floorf((x + 8.0f) * 256.0f);
  return min(max(b, 0), NB-1);
}

__device__ __forceinline__ unsigned short bf16_rne(float x){
  unsigned u = __float_as_uint(x);
  unsigned r = u + 0x7FFF + ((u >> 16) & 1);
  return (unsigned short)(r >> 16);
}

__device__ __forceinline__ float bfpair(unsigned short h, unsigned short l){
  return __uint_as_float(((unsigned)h) << 16) + __uint_as_float(((unsigned)l) << 16);
}

// async global->LDS, 16B per lane. LDS dest is WAVE-UNIFORM base + lane*16;
// global src is per-lane. Completion tracked by vmcnt.
__device__ __forceinline__ void gload16(const unsigned short* g, unsigned short* l){
  __builtin_amdgcn_global_load_lds(
      (__attribute__((address_space(1))) void*)g,
      (__attribute__((address_space(3))) void*)l, 16, 0, 0);
}

// bit-exact numpy distance key (r9-verified). Low 32 bits = original node idx.
__device__ __forceinline__ u64 make_key(float xi, float yi, float sqi,
                                        float cx, float cy, int jd, int self){
  float ax = cx*cx;  FPBAR(ax);
  float ay = cy*cy;  FPBAR(ay);
  float sqj = ax + ay;   FPBAR(sqj);
  float px = xi*cx;    FPBAR(px);
  float py = yi*cy;    FPBAR(py);
  float dt = px + py;    FPBAR(dt);            // NO-FMA dot
  float two_dt = 2.0f*dt;  FPBAR(two_dt);
  float ss = sqi + sqj;    FPBAR(ss);
  float d2 = ss - two_dt;  FPBAR(d2);
  float dist = __fsqrt_rn(fmaxf(d2, 0.0f));
  u64 key = ((u64)__float_as_uint(dist) << 32) | (unsigned)jd;
  return (jd == self) ? ~0ULL : key;
}

__device__ __forceinline__ void ladder_insert(u64* L, u64 key){
  bool c[KNN];
  #pragma unroll
  for (int t=0;t<KNN;t++) c[t] = key < L[t];
  #pragma unroll
  for (int t=KNN-1;t>=1;t--) L[t] = c[t-1] ? L[t-1] : (c[t] ? key : L[t]);
  L[0] = c[0] ? key : L[0];
}

// merge 64 candidate keys (one per lane) -> lane r holds r-th smallest (r<16).
__device__ __forceinline__ u64 merge64(const u64* m, int lane)
{
  u64 cur = m[lane];
  u64 out16 = ~0ULL;
  for (int r=0;r<KNN;r++){
    u64 k = cur; int who = lane;
    #pragma unroll
    for (int o=32;o>0;o>>=1){
      u64 ok = __shfl_xor(k, o, 64);
      int ow = __shfl_xor(who, o, 64);
      if (ok < k){ k = ok; who = ow; }
    }
    if (lane == r) out16 = k;
    if (lane == who) cur = ~0ULL;
  }
  return out16;
}

__device__ __forceinline__ void write_outputs(u64 out16, int lane, int n,
    int* __restrict__ idx_out, float* __restrict__ w_out)
{
  if (lane < KNN) idx_out[(size_t)n*KNN + lane] = (int)(unsigned)(out16 & 0xFFFFFFFFull);
  u64 kt[KNN];
  #pragma unroll
  for (int t=0;t<KNN;t++) kt[t] = __shfl(out16, t, 64);
  float inv[KNN];
  #pragma unroll
  for (int t=0;t<KNN;t++){
    float d = __uint_as_float((unsigned)(kt[t] >> 32));
    inv[t] = __fdiv_rn(1.0f, fmaxf(d, 1e-4f));
  }
  float r8v[8];
  #pragma unroll
  for (int t=0;t<8;t++){ r8v[t] = inv[t] + inv[t+8]; FPBAR(r8v[t]); }
  float s01 = r8v[0]+r8v[1]; FPBAR(s01);
  float s23 = r8v[2]+r8v[3]; FPBAR(s23);
  float s45 = r8v[4]+r8v[5]; FPBAR(s45);
  float s67 = r8v[6]+r8v[7]; FPBAR(s67);
  float sA = s01+s23; FPBAR(sA);
  float sB = s45+s67; FPBAR(sB);
  float s = sA + sB;
  s = fmaxf(s, 1e-8f);
  if (lane < KNN){
    float d = __uint_as_float((unsigned)(out16 >> 32));
    float invL = __fdiv_rn(1.0f, fmaxf(d, 1e-4f));
    w_out[(size_t)n*KNN + lane] = __fdiv_rn(invL, s);
  }
}

// compare-exchange macros for the bitonic network (named scalars only —
// r20/r28 lesson: u64 ARRAYS mutated through pointers/under exec-mask get
// lowered to scratch (VGPR 28/32 signatures). Named scalars stay in regs.
#define CE_A(x,y) { u64 mn_=(x)<(y)?(x):(y); u64 mx_=(x)<(y)?(y):(x); (x)=mn_; (y)=mx_; }
#define CE_D(x,y) { u64 mn_=(x)<(y)?(x):(y); u64 mx_=(x)<(y)?(y):(x); (x)=mx_; (y)=mn_; }

// LDS-free ballot tournament over NAMED scalars K0..K15 (r28/r30-proven).
#define TOURNEY16(out16, lane) {                                   \
    u64 cur = K0;                                                  \
    for (int r_=0;r_<KNN;r_++){                                    \
      u64 k_ = cur;                                                \
      _Pragma("unroll")                                            \
      for (int o_=32;o_>0;o_>>=1){                                 \
        u64 ok_ = __shfl_xor(k_, o_, 64);                          \
        if (ok_ < k_) k_ = ok_;                                    \
      }                                                            \
      u64 ball_ = __ballot(cur == k_);                             \
      int who_ = __ffsll(ball_) - 1;                               \
      if ((lane) == r_) out16 = k_;                                \
      if ((lane) == who_){                                         \
        K0=K1; K1=K2; K2=K3; K3=K4; K4=K5; K5=K6; K6=K7; K7=K8;    \
        K8=K9; K9=K10; K10=K11; K11=K12; K12=K13; K13=K14;         \
        K14=K15; K15=~0ULL;                                        \
        cur = K0;                                                  \
      }                                                            \
    }                                                              \
  }

// ---------------- dtype detection (proven: picks f32 here) ----------------
__global__ __launch_bounds__(256) void detect_kernel_r33(
    const unsigned* __restrict__ a, int na,
    const unsigned* __restrict__ b, int nb, int* __restrict__ flag)
{
  __shared__ int cnt;
  if (threadIdx.x == 0) cnt = 0;
  __syncthreads();
  int c = 0;
  for (int i = threadIdx.x; i < na; i += 256){
    int ex = (a[i] >> 7) & 0xFF;
    c += (ex >= 113 && ex <= 131) ? 1 : 0;
  }
  for (int i = threadIdx.x; i < nb; i += 256){
    int ex = (b[i] >> 7) & 0xFF;
    c += (ex >= 113 && ex <= 131) ? 1 : 0;
  }
  atomicAdd(&cnt, c);
  __syncthreads();
  if (threadIdx.x == 0) *flag = (cnt > (na + nb) / 2) ? 1 : 0;
}

// ---------------- decode all inputs to f32 workspace ----------------
struct SegTable {
  const void* src[16];
  float*      dst[16];
  int         cnt[16];
  int         total;
};

__global__ __launch_bounds__(256) void decode_kernel_r33(SegTable t,
    unsigned short* __restrict__ fh, unsigned short* __restrict__ fl,
    const int* __restrict__ flag)
{
  const int is_bf16 = *flag;
  for (int e = blockIdx.x*256 + threadIdx.x; e < t.total; e += gridDim.x*256){
    int rem = e, s = 0;
    while (rem >= t.cnt[s]){ rem -= t.cnt[s]; ++s; }
    float v;
    if (is_bf16) v = __uint_as_float(((unsigned)((const unsigned short*)t.src[s])[rem]) << 16);
    else         v = ((const float*)t.src[s])[rem];
    if (s == 0){
      unsigned short hb = bf16_rne(v);
      float hf = __uint_as_float(((unsigned)hb) << 16);
      fh[rem] = hb;
      fl[rem] = bf16_rne(v - hf);
    } else {
      t.dst[s][rem] = v;
    }
  }
}

// ---------------- weight pre-convert: fp32 -> bf16 hi/lo (once per launch) ----------------
struct WcTable { const float* src[6]; int cnt[6]; };

__global__ __launch_bounds__(256) void wconv_r33(WcTable t,
    unsigned short* __restrict__ dh, unsigned short* __restrict__ dl)
{
  for (int e = blockIdx.x*256 + threadIdx.x; e < NWELEM; e += gridDim.x*256){
    int rem = e, s = 0;
    while (rem >= t.cnt[s]){ rem -= t.cnt[s]; ++s; }
    float x = t.src[s][rem];
    unsigned short hb = bf16_rne(x);
    float hf = __uint_as_float(((unsigned)hb) << 16);
    dh[e] = hb;
    dl[e] = bf16_rne(x - hf);
  }
}

// ---------------- bucket pre-pass ----------------
__global__ __launch_bounds__(256) void zero_kernel_r33(int* __restrict__ hist, int* __restrict__ cursor,
                                                       int* __restrict__ ocnt)
{
  int t = blockIdx.x*256 + threadIdx.x;
  if (t < NB){ hist[t] = 0; cursor[t] = 0; }
  if (blockIdx.x == 0 && threadIdx.x == 0) *ocnt = 0;
}

__global__ __launch_bounds__(256) void count_kernel_r33(const float* __restrict__ cents,
                                                        int* __restrict__ hist)
{
  int i = blockIdx.x*256 + threadIdx.x;
  if (i < NND) atomicAdd(&hist[bucketof(cents[2*i])], 1);
}

__global__ __launch_bounds__(1024) void scan_kernel_r33(const int* __restrict__ hist,
                                                        int* __restrict__ offs)
{
  __shared__ int s[1024];
  int t = threadIdx.x;
  int h0 = hist[t*4], h1 = hist[t*4+1], h2 = hist[t*4+2], h3 = hist[t*4+3];
  int tot = h0+h1+h2+h3;
  s[t] = tot;
  __syncthreads();
  for (int d=1; d<1024; d<<=1){
    int v = (t >= d) ? s[t-d] : 0;
    __syncthreads();
    s[t] += v;
    __syncthreads();
  }
  int excl = s[t] - tot;
  offs[t*4]   = excl;
  offs[t*4+1] = excl + h0;
  offs[t*4+2] = excl + h0 + h1;
  offs[t*4+3] = excl + h0 + h1 + h2;
}

__global__ __launch_bounds__(256) void scatter_kernel_r33(const float* __restrict__ cents,
    const int* __restrict__ offs, int* __restrict__ cursor,
    float2* __restrict__ sxy, int* __restrict__ sid)
{
  int i = blockIdx.x*256 + threadIdx.x;
  if (i < NND){
    float x = cents[2*i], y = cents[2*i+1];
    int b = bucketof(x);
    int pos = offs[b] + atomicAdd(&cursor[b], 1);
    sxy[pos] = make_float2(x, y);
    sid[pos] = i;
  }
}

// ---------------- FUSED: encoder GEMM (blocks < EBLK) || knn_fixed (blocks >= EBLK) ----------------
// r33: ENCODER BLOCKS FIRST. r32's knn-first ordering meant the dispatcher
// filled all CUs with knn-only blocks for the first ~27us (1536 resident
// slots, 3000 knn blocks queued ahead of enc); overlap was partial (fused 70
// vs ideal max 54). Encoder-first puts both wave types on every CU from t=0
// so the latency-bound enc waves hide under the VALU-bound knn waves for the
// encoder's whole lifetime. ebid = bid (swizzle identity preserved);
// kbid = bid - EBLK (EBLK%4==0). Bodies byte-identical -> bit-identical.
__global__ __launch_bounds__(256, 4) void fused_enc_knn_r33(
    // encoder args
    const unsigned short* __restrict__ A1h, const unsigned short* __restrict__ A1l,
    const unsigned short* __restrict__ W1h, const unsigned short* __restrict__ W1l,
    const float* __restrict__ bias,
    unsigned short* __restrict__ Ch, unsigned short* __restrict__ Cl,
    // knn args
    const float2* __restrict__ sxy, const int* __restrict__ sid,
    const float* __restrict__ cents, const int* __restrict__ offs,
    int* __restrict__ idx_out, float* __restrict__ w_out,
    int* __restrict__ ocnt, int* __restrict__ olist, float* __restrict__ othr)
{
  __shared__ unsigned short sbW[3][2][2048];   // 24KB, encoder path only
  const int lane = threadIdx.x & 63, wv = threadIdx.x >> 6;

  if (blockIdx.x < EBLK){
    // ================= encoder body (mm_mfma_r30 <256,false,true,true>) ===========
    constexpr int NW = 2, NA = 2;
    constexpr int NCG = 4, LG = 2;
    constexpr int RTM = (NND + 63) / 64;   // 188
    const int ebid = blockIdx.x;
    const int xcd = ebid & 7;
    const int cg  = (ebid >> 3) & (NCG - 1);
    const int rt  = ((ebid >> (3 + LG)) << 3) + xcd;
    if (rt >= RTM) return;
    const int row0 = rt*64;
    const int n0 = cg*64;
    const int l15 = lane & 15;
    const int quad = lane >> 4;

    const size_t woff = (size_t)(n0 + lane) * DM;
    const unsigned short* wsrc = ((wv < 2) ? W1h : W1l) + woff;
    const int wtile = wv >> 1, q0 = (wv & 1) * 2;

    const int am = min(row0 + wv*16 + l15, NND-1);
    const size_t abase = (size_t)am*DM + quad*8;

    f4_t acc[4];
    #pragma unroll
    for (int t=0;t<4;t++) acc[t] = (f4_t){0.f,0.f,0.f,0.f};

    bf8_t A1H[3], A1L[3];

    auto STAGE = [&](int b, int ks){
      #pragma unroll
      for (int j=0;j<2;j++)
        gload16(wsrc + ks*32 + (q0+j)*8, &sbW[b][wtile][(q0+j)*512]);
    };
    auto LOADA = [&](int s, int ks){
      A1H[s] = *(const bf8_t*)(A1h + abase + ks*32);
      A1L[s] = *(const bf8_t*)(A1l + abase + ks*32);
    };

    STAGE(0, 0); LOADA(0, 0);
    STAGE(1, 1); LOADA(1, 1);
    constexpr int NKS = DM/32;             // 8
    #pragma unroll
    for (int ks=0; ks<NKS; ++ks){
      const int b = ks % 3;
      if (ks + 2 < NKS){ STAGE((ks+2)%3, ks+2); LOADA((ks+2)%3, ks+2); }
      if (ks + 2 < NKS)      asm volatile("s_waitcnt vmcnt(%0)" :: "i"(2*(NW+NA)) : "memory");
      else if (ks + 1 < NKS) asm volatile("s_waitcnt vmcnt(%0)" :: "i"(NW+NA) : "memory");
      else                   asm volatile("s_waitcnt vmcnt(0)" ::: "memory");
      __builtin_amdgcn_sched_barrier(0);
      __builtin_amdgcn_s_barrier();
      __builtin_amdgcn_sched_barrier(0);
      {
        bf8_t a1h = A1H[b], a1l = A1L[b];
        #pragma unroll
        for (int t=0;t<4;t++){
          const int wr = quad*512 + (t*16 + l15)*8;
          bf8_t bh = *(const bf8_t*)&sbW[b][0][wr];
          bf8_t bl = *(const bf8_t*)&sbW[b][1][wr];
          acc[t] = __builtin_amdgcn_mfma_f32_16x16x32_bf16(a1h, bh, acc[t], 0, 0, 0);
          acc[t] = __builtin_amdgcn_mfma_f32_16x16x32_bf16(a1h, bl, acc[t], 0, 0, 0);
          acc[t] = __builtin_amdgcn_mfma_f32_16x16x32_bf16(a1l, bh, acc[t], 0, 0, 0);
        }
      }
      __builtin_amdgcn_sched_barrier(0);
      asm volatile("s_waitcnt lgkmcnt(0)" ::: "memory");
      __builtin_amdgcn_s_barrier();
      __builtin_amdgcn_sched_barrier(0);
    }

    #pragma unroll
    for (int t=0;t<4;t++){
      int n = n0 + t*16 + l15;
      float bv = bias[n];
      #pragma unroll
      for (int r=0;r<4;r++){
        int row = row0 + wv*16 + quad*4 + r;
        if (row < NND){
          float v = geluf(acc[t][r] + bv);
          unsigned short hb = bf16_rne(v);
          float hf = __uint_as_float(((unsigned)hb) << 16);
          Ch[(size_t)row*DM + n] = hb;
          Cl[(size_t)row*DM + n] = bf16_rne(v - hf);
        }
      }
    }
    return;
  }

  // ================= knn_fixed body (r30: named-scalar + shift tournament, LDS-free) =====
  const int n = (blockIdx.x - EBLK)*4 + wv;
  const float xi = cents[2*n];
  const float yi = cents[2*n+1];
  float sx = xi*xi; FPBAR(sx);
  float sy = yi*yi; FPBAR(sy);
  float sqi = sx + sy; FPBAR(sqi);

  const int start = offs[bucketof(xi)];
  const bool isR = lane < 32;
  const int lo = isR ? lane : (lane - 32);

  u64 K0,K1,K2,K3,K4,K5,K6,K7,K8,K9,K10,K11,K12,K13,K14,K15;
  #define KROUND(r, K) { \
    int myp = isR ? (start + (r)*32 + lo) : (start - 1 - (r)*32 - lo); \
    bool act = (myp >= 0) && (myp < NND); \
    float2 cu = make_float2(0.f, 0.f); \
    int jd = -1; \
    if (act){ cu = sxy[myp]; jd = sid[myp]; } \
    u64 key = make_key(xi, yi, sqi, cu.x, cu.y, jd, n); \
    K = act ? key : ~0ULL; }
  KROUND(0,K0)   KROUND(1,K1)   KROUND(2,K2)   KROUND(3,K3)
  KROUND(4,K4)   KROUND(5,K5)   KROUND(6,K6)   KROUND(7,K7)
  KROUND(8,K8)   KROUND(9,K9)   KROUND(10,K10) KROUND(11,K11)
  KROUND(12,K12) KROUND(13,K13) KROUND(14,K14) KROUND(15,K15)
  #undef KROUND

  // bitonic sort network, 16 keys ascending (80 compare-exchanges, static)
  CE_A(K0,K1)  CE_D(K2,K3)  CE_A(K4,K5)  CE_D(K6,K7)
  CE_A(K8,K9)  CE_D(K10,K11) CE_A(K12,K13) CE_D(K14,K15)
  CE_A(K0,K2)  CE_A(K1,K3)  CE_D(K4,K6)  CE_D(K5,K7)
  CE_A(K8,K10) CE_A(K9,K11) CE_D(K12,K14) CE_D(K13,K15)
  CE_A(K0,K1)  CE_A(K2,K3)  CE_D(K4,K5)  CE_D(K6,K7)
  CE_A(K8,K9)  CE_A(K10,K11) CE_D(K12,K13) CE_D(K14,K15)
  CE_A(K0,K4)  CE_A(K1,K5)  CE_A(K2,K6)  CE_A(K3,K7)
  CE_D(K8,K12) CE_D(K9,K13) CE_D(K10,K14) CE_D(K11,K15)
  CE_A(K0,K2)  CE_A(K1,K3)  CE_A(K4,K6)  CE_A(K5,K7)
  CE_D(K8,K10) CE_D(K9,K11) CE_D(K12,K14) CE_D(K13,K15)
  CE_A(K0,K1)  CE_A(K2,K3)  CE_A(K4,K5)  CE_A(K6,K7)
  CE_D(K8,K9)  CE_D(K10,K11) CE_D(K12,K13) CE_D(K14,K15)
  CE_A(K0,K8)  CE_A(K1,K9)  CE_A(K2,K10) CE_A(K3,K11)
  CE_A(K4,K12) CE_A(K5,K13) CE_A(K6,K14) CE_A(K7,K15)
  CE_A(K0,K4)  CE_A(K1,K5)  CE_A(K2,K6)  CE_A(K3,K7)
  CE_A(K8,K12) CE_A(K9,K13) CE_A(K10,K14) CE_A(K11,K15)
  CE_A(K0,K2)  CE_A(K1,K3)  CE_A(K4,K6)  CE_A(K5,K7)
  CE_A(K8,K10) CE_A(K9,K11) CE_A(K12,K14) CE_A(K13,K15)
  CE_A(K0,K1)  CE_A(K2,K3)  CE_A(K4,K5)  CE_A(K6,K7)
  CE_A(K8,K9)  CE_A(K10,K11) CE_A(K12,K13) CE_A(K14,K15)

  u64 out16 = ~0ULL;
  TOURNEY16(out16, lane)

  float B = __uint_as_float((unsigned)(__shfl(out16, KNN-1, 64) >> 32));
  const float thr = B*B + 2e-4f;

  const int qr = min(start + RW*32, NND);
  const int ql = max(start - RW*32, 0);
  bool ok;
  {
    bool rok = (qr >= NND);
    if (!rok){
      float xR = sxy[qr-1].x;
      float dxr = ((float)bucketof(xR)*BW - 8.0f) - xi;
      rok = (dxr > 0.0f) && (dxr*dxr > thr);
    }
    bool lok = (ql <= 0);
    if (!lok){
      float xL = sxy[ql].x;
      float dxl = xi - ((float)(bucketof(xL)+1)*BW - 8.0f);
      lok = (dxl > 0.0f) && (dxl*dxl > thr);
    }
    ok = rok && lok;
  }
  if (lane == 0 && !ok){
    int s = atomicAdd(ocnt, 1);
    olist[s] = n;
    othr[s] = thr;
  }

  write_outputs(out16, lane, n, idx_out, w_out);
}

// ---------------- bounded rescan for deferred nodes ----------------
// r29-proven: array ladder (register-resident) + copy to named scalars +
// inline tournament. Bit-identical outputs.
__global__ __launch_bounds__(256, 4) void knn_ext_r33(
    const float2* __restrict__ sxy, const int* __restrict__ sid,
    const float* __restrict__ cents, const int* __restrict__ offs,
    const int* __restrict__ olist, const float* __restrict__ othr,
    const int* __restrict__ ocnt,
    int* __restrict__ idx_out, float* __restrict__ w_out)
{
  __shared__ u64 merged[64];         // 4 waves x 16 survivors
  const int lane = threadIdx.x & 63, wv = threadIdx.x >> 6;
  const int cnt = *ocnt;

  for (int slot = blockIdx.x; slot < cnt; slot += gridDim.x){
    const int n = olist[slot];
    const float thr = othr[slot];
    const float rB = __fsqrt_rn(thr) * (1.0f + 2e-6f);
    const float xi = cents[2*n];
    const float yi = cents[2*n+1];
    float sx = xi*xi; FPBAR(sx);
    float sy = yi*yi; FPBAR(sy);
    float sqi = sx + sy; FPBAR(sqi);

    const int bL = bucketof(xi - rB);
    const int bR = bucketof(xi + rB);
    const int posL = offs[bL];
    const int posR = (bR + 1 < NB) ? offs[bR + 1] : NND;

    u64 L[KNN];
    #pragma unroll
    for (int t=0;t<KNN;t++) L[t] = ~0ULL;

    int p = posL + (wv<<6) + lane;
    for (; p + 256 < posR; p += 512){
      float2 c0 = sxy[p];       int j0 = sid[p];
      float2 c1 = sxy[p+256];   int j1 = sid[p+256];
      u64 k0 = make_key(xi, yi, sqi, c0.x, c0.y, j0, n);
      u64 k1 = make_key(xi, yi, sqi, c1.x, c1.y, j1, n);
      if (k0 < L[KNN-1]) ladder_insert(L, k0);   // exact: key>=L[15] is a no-op
      if (k1 < L[KNN-1]) ladder_insert(L, k1);
    }
    if (p < posR){
      float2 c0 = sxy[p];
      u64 k0 = make_key(xi, yi, sqi, c0.x, c0.y, sid[p], n);
      if (k0 < L[KNN-1]) ladder_insert(L, k0);
    }

    // copy to named scalars (static) -> spill-proof tournament
    u64 K0=L[0], K1=L[1], K2=L[2],  K3=L[3],  K4=L[4],  K5=L[5],  K6=L[6],  K7=L[7],
        K8=L[8], K9=L[9], K10=L[10],K11=L[11],K12=L[12],K13=L[13],K14=L[14],K15=L[15];
    u64 w16 = ~0ULL;
    TOURNEY16(w16, lane)

    if (lane < KNN) merged[(wv<<4) + lane] = w16;
    __syncthreads();
    if (wv == 0){
      u64 out16 = merge64(merged, lane);
      write_outputs(out16, lane, n, idx_out, w_out);
    }
    __syncthreads();   // merged[] reused next slot
  }
}

// ---------------- GEMM: W-in-LDS (depth-2 prefetch) + A-in-registers ----------------
// r30-proven: A per-lane register loads (triple-buffered), W-only LDS with 3
// buffers (depth-2 counted vmcnt), XCD-local swizzle. Unchanged.
template<int OUT, bool DUAL, bool BIAS, bool SPLITOUT>
__global__ __launch_bounds__(256, 4) void mm_mfma_r33(
    const unsigned short* __restrict__ A1h, const unsigned short* __restrict__ A1l,
    const unsigned short* __restrict__ A2h, const unsigned short* __restrict__ A2l,
    const unsigned short* __restrict__ W1h, const unsigned short* __restrict__ W1l,
    const unsigned short* __restrict__ W2h, const unsigned short* __restrict__ W2l,
    const float* __restrict__ bias,
    float* __restrict__ Cf, unsigned short* __restrict__ Ch, unsigned short* __restrict__ Cl)
{
  constexpr int NTILW = DUAL ? 4 : 2;      // W tiles per k-step
  constexpr int NW  = DUAL ? 4 : 2;        // W gload_lds per wave per step
  constexpr int NA  = DUAL ? 4 : 2;        // A register loads per lane per step
  constexpr int NCG = OUT / 64;            // 4 or 2
  constexpr int LG  = (NCG == 4) ? 2 : 1;
  constexpr int RTM = (NND + 63) / 64;     // 188
  __shared__ unsigned short sbW[3][NTILW][2048];   // 3 buffers x W tiles x 4KB
  const int lane = threadIdx.x & 63, wv = threadIdx.x >> 6;
  const int bid = blockIdx.x;
  const int xcd = bid & 7;
  const int cg  = (bid >> 3) & (NCG - 1);
  const int rt  = ((bid >> (3 + LG)) << 3) + xcd;
  if (rt >= RTM) return;
  const int row0 = rt*64;
  const int n0 = cg*64;
  const int l15 = lane & 15;
  const int quad = lane >> 4;

  // W staging: DUAL -> wave wv stages tile wv (4 gloads, one per quad);
  // non-dual -> wave wv stages tile wv>>1, quads {(wv&1)*2, (wv&1)*2+1}.
  const size_t woff = (size_t)(n0 + lane) * DM;
  const unsigned short* wsrc;
  int wtile, q0;
  if (DUAL){
    wsrc = ((wv==0) ? W1h : (wv==1) ? W1l : (wv==2) ? W2h : W2l) + woff;
    wtile = wv; q0 = 0;
  } else {
    wsrc = ((wv < 2) ? W1h : W1l) + woff;
    wtile = wv >> 1; q0 = (wv & 1) * 2;
  }

  // A direct per-lane source (this lane's MFMA A-fragment row)
  const int am = min(row0 + wv*16 + l15, NND-1);
  const size_t abase = (size_t)am*DM + quad*8;

  f4_t acc[4];
  #pragma unroll
  for (int t=0;t<4;t++) acc[t] = (f4_t){0.f,0.f,0.f,0.f};

  bf8_t A1H[3], A1L[3], A2H[3], A2L[3];

  auto STAGE = [&](int b, int ks){
    if (DUAL){
      #pragma unroll
      for (int j=0;j<4;j++)
        gload16(wsrc + ks*32 + j*8, &sbW[b][wtile][j*512]);
    } else {
      #pragma unroll
      for (int j=0;j<2;j++)
        gload16(wsrc + ks*32 + (q0+j)*8, &sbW[b][wtile][(q0+j)*512]);
    }
  };
  auto LOADA = [&](int s, int ks){
    A1H[s] = *(const bf8_t*)(A1h + abase + ks*32);
    A1L[s] = *(const bf8_t*)(A1l + abase + ks*32);
    if (DUAL){
      A2H[s] = *(const bf8_t*)(A2h + abase + ks*32);
      A2L[s] = *(const bf8_t*)(A2l + abase + ks*32);
    }
  };

  STAGE(0, 0); LOADA(0, 0);
  STAGE(1, 1); LOADA(1, 1);
  constexpr int NKS = DM/32;             // 8
  #pragma unroll
  for (int ks=0; ks<NKS; ++ks){
    const int b = ks % 3;
    if (ks + 2 < NKS){ STAGE((ks+2)%3, ks+2); LOADA((ks+2)%3, ks+2); }
    // wait for step ks's loads: newer = steps ks+1 (and ks+2 if issued)
    if (ks + 2 < NKS)      asm volatile("s_waitcnt vmcnt(%0)" :: "i"(2*(NW+NA)) : "memory");
    else if (ks + 1 < NKS) asm volatile("s_waitcnt vmcnt(%0)" :: "i"(NW+NA) : "memory");
    else                   asm volatile("s_waitcnt vmcnt(0)" ::: "memory");
    __builtin_amdgcn_sched_barrier(0);
    __builtin_amdgcn_s_barrier();        // all waves: W tiles for ks complete
    __builtin_amdgcn_sched_barrier(0);
    {
      bf8_t a1h = A1H[b], a1l = A1L[b];
      bf8_t a2h, a2l;
      if (DUAL){ a2h = A2H[b]; a2l = A2L[b]; }
      #pragma unroll
      for (int t=0;t<4;t++){
        const int wr = quad*512 + (t*16 + l15)*8;
        bf8_t bh = *(const bf8_t*)&sbW[b][0][wr];
        bf8_t bl = *(const bf8_t*)&sbW[b][1][wr];
        acc[t] = __builtin_amdgcn_mfma_f32_16x16x32_bf16(a1h, bh, acc[t], 0, 0, 0);
        acc[t] = __builtin_amdgcn_mfma_f32_16x16x32_bf16(a1h, bl, acc[t], 0, 0, 0);
        acc[t] = __builtin_amdgcn_mfma_f32_16x16x32_bf16(a1l, bh, acc[t], 0, 0, 0);
        if (DUAL){
          bf8_t ch = *(const bf8_t*)&sbW[b][2][wr];
          bf8_t cl = *(const bf8_t*)&sbW[b][3][wr];
          acc[t] = __builtin_amdgcn_mfma_f32_16x16x32_bf16(a2h, ch, acc[t], 0, 0, 0);
          acc[t] = __builtin_amdgcn_mfma_f32_16x16x32_bf16(a2h, cl, acc[t], 0, 0, 0);
          acc[t] = __builtin_amdgcn_mfma_f32_16x16x32_bf16(a2l, ch, acc[t], 0, 0, 0);
        }
      }
    }
    __builtin_amdgcn_sched_barrier(0);
    asm volatile("s_waitcnt lgkmcnt(0)" ::: "memory");
    __builtin_amdgcn_s_barrier();        // all waves done reading buffer b
    __builtin_amdgcn_sched_barrier(0);
  }

  #pragma unroll
  for (int t=0;t<4;t++){
    int n = n0 + t*16 + l15;
    float bv = BIAS ? bias[n] : 0.f;
    #pragma unroll
    for (int r=0;r<4;r++){
      int row = row0 + wv*16 + quad*4 + r;
      if (row < NND){
        float v = geluf(acc[t][r] + bv);
        if (SPLITOUT){
          unsigned short hb = bf16_rne(v);
          float hf = __uint_as_float(((unsigned)hb) << 16);
          Ch[(size_t)row*OUT + n] = hb;
          Cl[(size_t)row*OUT + n] = bf16_rne(v - hf);
        } else {
          Cf[(size_t)row*OUT + n] = v;
        }
      }
    }
  }
}

// ---------------- weighted neighbor aggregation ----------------
__global__ __launch_bounds__(256) void agg_kernel_r33(
    const unsigned short* __restrict__ hh, const unsigned short* __restrict__ hl,
    const int* __restrict__ idx, const float* __restrict__ w,
    unsigned short* __restrict__ oh, unsigned short* __restrict__ ol)
{
  const int lane = threadIdx.x & 63, wid = threadIdx.x >> 6;
  const int n = blockIdx.x*4 + wid;
  const int base = n*KNN;
  const int c = lane*4;
  float4 acc = make_float4(0.f,0.f,0.f,0.f);
  for (int k=0;k<KNN;k++){
    int j = idx[base+k];
    float wk = w[base+k];
    ushort4 vh = *(const ushort4*)(hh + (size_t)j*DM + c);
    ushort4 vl = *(const ushort4*)(hl + (size_t)j*DM + c);
    acc.x = fmaf(wk, bfpair(vh.x, vl.x), acc.x);
    acc.y = fmaf(wk, bfpair(vh.y, vl.y), acc.y);
    acc.z = fmaf(wk, bfpair(vh.z, vl.z), acc.z);
    acc.w = fmaf(wk, bfpair(vh.w, vl.w), acc.w);
  }
  unsigned short h0 = bf16_rne(acc.x); float f0 = __uint_as_float(((unsigned)h0) << 16);
  unsigned short h1 = bf16_rne(acc.y); float f1 = __uint_as_float(((unsigned)h1) << 16);
  unsigned short h2 = bf16_rne(acc.z); float f2 = __uint_as_float(((unsigned)h2) << 16);
  unsigned short h3 = bf16_rne(acc.w); float f3 = __uint_as_float(((unsigned)h3) << 16);
  ushort4 sh = make_ushort4(h0, h1, h2, h3);
  ushort4 sl = make_ushort4(bf16_rne(acc.x - f0), bf16_rne(acc.y - f1),
                            bf16_rne(acc.z - f2), bf16_rne(acc.w - f3));
  *(ushort4*)(oh + (size_t)n*DM + c) = sh;
  *(ushort4*)(ol + (size_t)n*DM + c) = sl;
}

// ---------------- h = h + layernorm(tmp)*g + b  (h stored as bf16 hi/lo) ----------------
__global__ __launch_bounds__(256) void ln_res_kernel_r33(
    unsigned short* __restrict__ hh, unsigned short* __restrict__ hl,
    const float* __restrict__ tmp, const float* __restrict__ g, const float* __restrict__ b)
{
  const int lane = threadIdx.x & 63, wid = threadIdx.x >> 6;
  const int n = blockIdx.x*4 + wid;
  float4 x = *(const float4*)(tmp + (size_t)n*DM + lane*4);
  float s = (x.x + x.y) + (x.z + x.w);
  #pragma unroll
  for (int off=32; off>0; off>>=1) s += __shfl_xor(s, off, 64);
  float mu = s * (1.0f/DM);
  float dx0 = x.x-mu, dx1 = x.y-mu, dx2 = x.z-mu, dx3 = x.w-mu;
  float v = (dx0*dx0 + dx1*dx1) + (dx2*dx2 + dx3*dx3);
  #pragma unroll
  for (int off=32; off>0; off>>=1) v += __shfl_xor(v, off, 64);
  float rs = 1.0f / sqrtf(v * (1.0f/DM) + 1e-5f);
  int c = lane*4;
  float4 gv = *(const float4*)(g + c);
  float4 bv = *(const float4*)(b + c);
  ushort4 vh = *(const ushort4*)(hh + (size_t)n*DM + c);
  ushort4 vl = *(const ushort4*)(hl + (size_t)n*DM + c);
  float o0 = bfpair(vh.x, vl.x) + dx0*rs*gv.x + bv.x;
  float o1 = bfpair(vh.y, vl.y) + dx1*rs*gv.y + bv.y;
  float o2 = bfpair(vh.z, vl.z) + dx2*rs*gv.z + bv.z;
  float o3 = bfpair(vh.w, vl.w) + dx3*rs*gv.w + bv.w;
  unsigned short h0 = bf16_rne(o0); float f0 = __uint_as_float(((unsigned)h0) << 16);
  unsigned short h1 = bf16_rne(o1); float f1 = __uint_as_float(((unsigned)h1) << 16);
  unsigned short h2 = bf16_rne(o2); float f2 = __uint_as_float(((unsigned)h2) << 16);
  unsigned short h3 = bf16_rne(o3); float f3 = __uint_as_float(((unsigned)h3) << 16);
  *(ushort4*)(hh + (size_t)n*DM + c) = make_ushort4(h0, h1, h2, h3);
  *(ushort4*)(hl + (size_t)n*DM + c) = make_ushort4(bf16_rne(o0 - f0), bf16_rne(o1 - f1),
                                                    bf16_rne(o2 - f2), bf16_rne(o3 - f3));
}

// ---------------- final: out[n] = sigmoid(dot(hid[n], w2) + b2), dtype per flag ----------------
__global__ __launch_bounds__(256) void cls2_kernel_r33(const float* __restrict__ hid,
    const float* __restrict__ w2, const float* __restrict__ b2,
    void* __restrict__ out, const int* __restrict__ flag)
{
  const int lane = threadIdx.x & 63, wid = threadIdx.x >> 6;
  const int n = blockIdx.x*4 + wid;
  float a = hid[(size_t)n*128 + lane]      * w2[lane]
          + hid[(size_t)n*128 + 64 + lane] * w2[64+lane];
  #pragma unroll
  for (int off=32; off>0; off>>=1) a += __shfl_xor(a, off, 64);
  if (lane == 0){
    float v = 1.0f / (1.0f + expf(-(a + b2[0])));
    if (*flag) ((__hip_bfloat16*)out)[n] = __float2bfloat16(v);
    else       ((float*)out)[n] = v;
  }
}

extern "C" void kernel_launch(void* const* d_in, const int* in_sizes, int n_in,
                              void* d_out, int out_size, void* d_ws, size_t ws_size,
                              hipStream_t stream)
{
  // ---- workspace layout (~46.5 MB), fully rewritten every call ----
  char* base = (char*)d_ws;
  int*   flag = (int*)base;                                   // 16 B slot
  float* wreg = (float*)(base + 16);
  static const int sizes[16] = {
    NND*256, NND*2, 256*256, 256, 256*256, 256*256, 256, 256,
    256*256, 256*256, 256, 256, 128*256, 128, 128, 1
  };
  float* ptrs[16];
  {
    float* p = wreg;
    for (int i = 2; i < 16; i++){ ptrs[i] = p; p += (sizes[i] + 3) & ~3; }
    ptrs[1] = p;                          // cents  [24,000]
    p += NND*2;
    ptrs[0] = p;                          // feats region  [3,072,000 floats]
  }
  float* F    = ptrs[0];                  // f32 tmp view of feats region
  unsigned short* fh = (unsigned short*)ptrs[0];          // feats hi
  unsigned short* fl = fh + (size_t)NND*DM;               // feats lo
  float* C    = ptrs[1];
  float* hbase = F + (size_t)NND*DM;
  unsigned short* h_hi = (unsigned short*)hbase;
  unsigned short* h_lo = h_hi + (size_t)NND*DM;
  float* abase = hbase + (size_t)NND*DM;
  unsigned short* a_hi = (unsigned short*)abase;
  unsigned short* a_lo = a_hi + (size_t)NND*DM;
  float* hid  = abase + (size_t)NND*DM;
  int*  gidx  = (int*)(hid + (size_t)NND*128);
  float* gw   = (float*)(gidx + (size_t)NND*KNN);
  // knn pre-pass scratch
  float2* sxy   = (float2*)(gw + (size_t)NND*KNN);
  int*    sid   = (int*)(sxy + NND);
  int*    hist  = sid + NND;
  int*    cursor= hist + NB;
  int*    offs  = cursor + NB;
  int*    ocnt  = offs + NB;
  int*    olist = ocnt + 4;               // 16B pad keeps wh 16B-aligned
  float*  othr  = (float*)(olist + NND);  // thr per deferred node
  // bf16 hi/lo weights (enc_w | g1_ws | g1_wn | g2_ws | g2_wn | cls_w1), 16B-aligned
  unsigned short* wh = (unsigned short*)(((uintptr_t)(othr + NND) + 15) & ~(uintptr_t)15);
  unsigned short* wl = wh + NWELEM;

  // ---- dtype detect + decode ----
  detect_kernel_r33<<<1, 256, 0, stream>>>((const unsigned*)d_in[1], 4096,
                                           (const unsigned*)d_in[0], 16384, flag);
  SegTable t;
  int total = 0;
  for (int i = 0; i < 16; i++){
    t.src[i] = d_in[i];
    t.dst[i] = ptrs[i];
    t.cnt[i] = sizes[i];
    total += sizes[i];
  }
  t.dst[0] = nullptr;   // feats handled via fh/fl
  t.total = total;
  decode_kernel_r33<<<(total + 255)/256, 256, 0, stream>>>(t, fh, fl, flag);

  const float* enc_b  = ptrs[3];
  const float* g1_g   = ptrs[6];  const float* g1_b   = ptrs[7];
  const float* g2_g   = ptrs[10]; const float* g2_b   = ptrs[11];
  const float* cls_b1 = ptrs[13];
  const float* cls_w2 = ptrs[14]; const float* cls_b2 = ptrs[15];

  // weight bf16 hi/lo conversion (after decode)
  WcTable wt;
  wt.src[0] = ptrs[2];  wt.cnt[0] = 65536;   // enc_w
  wt.src[1] = ptrs[4];  wt.cnt[1] = 65536;   // g1_ws
  wt.src[2] = ptrs[5];  wt.cnt[2] = 65536;   // g1_wn
  wt.src[3] = ptrs[8];  wt.cnt[3] = 65536;   // g2_ws
  wt.src[4] = ptrs[9];  wt.cnt[4] = 65536;   // g2_wn
  wt.src[5] = ptrs[12]; wt.cnt[5] = 32768;   // cls_w1
  wconv_r33<<<512, 256, 0, stream>>>(wt, wh, wl);

  dim3 b256(256);
  // knn pre-pass: bucket counting sort by x (+ zero outlier counter)
  zero_kernel_r33<<<(NB + 255)/256, b256, 0, stream>>>(hist, cursor, ocnt);
  count_kernel_r33<<<(NND + 255)/256, b256, 0, stream>>>(C, hist);
  scan_kernel_r33<<<1, 1024, 0, stream>>>(hist, offs);
  scatter_kernel_r33<<<(NND + 255)/256, b256, 0, stream>>>(C, offs, cursor, sxy, sid);
  // swizzled grids: 24 rt-groups of 8 XCD-slots x NCG col-groups
  const int G4 = 24 * 8 * 4;   // 768  (OUT=256)
  const int G2 = 24 * 8 * 2;   // 384  (OUT=128)
  // FUSED: encoder GEMM (blocks 0..767) || knn_fixed (blocks 768..3767)
  fused_enc_knn_r33<<<EBLK + NND/4, b256, 0, stream>>>(
      fh, fl, wh + 0, wl + 0, enc_b, h_hi, h_lo,
      sxy, sid, C, offs, gidx, gw, ocnt, olist, othr);
  knn_ext_r33<<<2048, b256, 0, stream>>>(sxy, sid, C, offs, olist, othr, ocnt, gidx, gw);
  // sage layer 1 (tmp := F region, feats dead after encoder)
  agg_kernel_r33<<<NND/4, b256, 0, stream>>>(h_hi, h_lo, gidx, gw, a_hi, a_lo);
  mm_mfma_r33<256,true,false,false><<<G4, b256, 0, stream>>>(h_hi, h_lo, a_hi, a_lo,
      wh + 65536, wl + 65536, wh + 131072, wl + 131072, nullptr, F, nullptr, nullptr);
  ln_res_kernel_r33<<<NND/4, b256, 0, stream>>>(h_hi, h_lo, F, g1_g, g1_b);
  // sage layer 2
  agg_kernel_r33<<<NND/4, b256, 0, stream>>>(h_hi, h_lo, gidx, gw, a_hi, a_lo);
  mm_mfma_r33<256,true,false,false><<<G4, b256, 0, stream>>>(h_hi, h_lo, a_hi, a_lo,
      wh + 196608, wl + 196608, wh + 262144, wl + 262144, nullptr, F, nullptr, nullptr);
  ln_res_kernel_r33<<<NND/4, b256, 0, stream>>>(h_hi, h_lo, F, g2_g, g2_b);
  // classifier
  mm_mfma_r33<128,false,true,false><<<G2, b256, 0, stream>>>(h_hi, h_lo, nullptr, nullptr,
      wh + 327680, wl + 327680, nullptr, nullptr, cls_b1, hid, nullptr, nullptr);
  cls2_kernel_r33<<<NND/4, b256, 0, stream>>>(hid, cls_w2, cls_b2, d_out, flag);
}

// Round 16
// 375.507 us; speedup vs baseline: 1.0273x; 1.0273x over previous
//
#include <hip/hip_runtime.h>
#include <hip/hip_bf16.h>
#include <stdint.h>

#define NND 12000
#define DM  256
#define KNN 16
#define NB  4096          // x-buckets
#define BW  0.00390625f   // bucket width = 1/256 over [-8, 8)
#define RW  16            // fixed-window rounds (16*64 = 1024 candidates)
#define NWELEM 360448     // total weight elements converted to bf16 hi/lo
#define KBLK (NND/4)      // 3000 knn blocks first (r32 ordering, measured best)

// Opaque register barrier: prevents FMA contraction (r9: made knn bit-match numpy
// -> absmax 0.0. DO NOT REMOVE from knn path).
#define FPBAR(x) asm volatile("" : "+v"(x))

typedef unsigned long long u64;
typedef __attribute__((ext_vector_type(8))) short bf8_t;   // 8 bf16 (4 VGPRs)
typedef __attribute__((ext_vector_type(4))) float f4_t;

__device__ __forceinline__ float geluf(float x){ return 0.5f*x*(1.0f + erff(x*0.70710678118654752f)); }
__device__ __forceinline__ int bucketof(float x){
  int b = (int)floorf((x + 8.0f) * 256.0f);
  return min(max(b, 0), NB-1);
}

__device__ __forceinline__ unsigned short bf16_rne(float x){
  unsigned u = __float_as_uint(x);
  unsigned r = u + 0x7FFF + ((u >> 16) & 1);
  return (unsigned short)(r >> 16);
}

__device__ __forceinline__ float bfpair(unsigned short h, unsigned short l){
  return __uint_as_float(((unsigned)h) << 16) + __uint_as_float(((unsigned)l) << 16);
}

// async global->LDS, 16B per lane. LDS dest is WAVE-UNIFORM base + lane*16;
// global src is per-lane. Completion tracked by vmcnt.
__device__ __forceinline__ void gload16(const unsigned short* g, unsigned short* l){
  __builtin_amdgcn_global_load_lds(
      (__attribute__((address_space(1))) void*)g,
      (__attribute__((address_space(3))) void*)l, 16, 0, 0);
}

// bit-exact numpy distance key (r9-verified). Low 32 bits = original node idx.
__device__ __forceinline__ u64 make_key(float xi, float yi, float sqi,
                                        float cx, float cy, int jd, int self){
  float ax = cx*cx;  FPBAR(ax);
  float ay = cy*cy;  FPBAR(ay);
  float sqj = ax + ay;   FPBAR(sqj);
  float px = xi*cx;    FPBAR(px);
  float py = yi*cy;    FPBAR(py);
  float dt = px + py;    FPBAR(dt);            // NO-FMA dot
  float two_dt = 2.0f*dt;  FPBAR(two_dt);
  float ss = sqi + sqj;    FPBAR(ss);
  float d2 = ss - two_dt;  FPBAR(d2);
  float dist = __fsqrt_rn(fmaxf(d2, 0.0f));
  u64 key = ((u64)__float_as_uint(dist) << 32) | (unsigned)jd;
  return (jd == self) ? ~0ULL : key;
}

__device__ __forceinline__ void ladder_insert(u64* L, u64 key){
  bool c[KNN];
  #pragma unroll
  for (int t=0;t<KNN;t++) c[t] = key < L[t];
  #pragma unroll
  for (int t=KNN-1;t>=1;t--) L[t] = c[t-1] ? L[t-1] : (c[t] ? key : L[t]);
  L[0] = c[0] ? key : L[0];
}

// merge 64 candidate keys (one per lane) -> lane r holds r-th smallest (r<16).
__device__ __forceinline__ u64 merge64(const u64* m, int lane)
{
  u64 cur = m[lane];
  u64 out16 = ~0ULL;
  for (int r=0;r<KNN;r++){
    u64 k = cur; int who = lane;
    #pragma unroll
    for (int o=32;o>0;o>>=1){
      u64 ok = __shfl_xor(k, o, 64);
      int ow = __shfl_xor(who, o, 64);
      if (ok < k){ k = ok; who = ow; }
    }
    if (lane == r) out16 = k;
    if (lane == who) cur = ~0ULL;
  }
  return out16;
}

__device__ __forceinline__ void write_outputs(u64 out16, int lane, int n,
    int* __restrict__ idx_out, float* __restrict__ w_out)
{
  if (lane < KNN) idx_out[(size_t)n*KNN + lane] = (int)(unsigned)(out16 & 0xFFFFFFFFull);
  u64 kt[KNN];
  #pragma unroll
  for (int t=0;t<KNN;t++) kt[t] = __shfl(out16, t, 64);
  float inv[KNN];
  #pragma unroll
  for (int t=0;t<KNN;t++){
    float d = __uint_as_float((unsigned)(kt[t] >> 32));
    inv[t] = __fdiv_rn(1.0f, fmaxf(d, 1e-4f));
  }
  float r8v[8];
  #pragma unroll
  for (int t=0;t<8;t++){ r8v[t] = inv[t] + inv[t+8]; FPBAR(r8v[t]); }
  float s01 = r8v[0]+r8v[1]; FPBAR(s01);
  float s23 = r8v[2]+r8v[3]; FPBAR(s23);
  float s45 = r8v[4]+r8v[5]; FPBAR(s45);
  float s67 = r8v[6]+r8v[7]; FPBAR(s67);
  float sA = s01+s23; FPBAR(sA);
  float sB = s45+s67; FPBAR(sB);
  float s = sA + sB;
  s = fmaxf(s, 1e-8f);
  if (lane < KNN){
    float d = __uint_as_float((unsigned)(out16 >> 32));
    float invL = __fdiv_rn(1.0f, fmaxf(d, 1e-4f));
    w_out[(size_t)n*KNN + lane] = __fdiv_rn(invL, s);
  }
}

// compare-exchange macros for the bitonic network (named scalars only —
// r20/r28 lesson: u64 ARRAYS mutated through pointers/under exec-mask get
// lowered to scratch (VGPR 28/32 signatures). Named scalars stay in regs.
#define CE_A(x,y) { u64 mn_=(x)<(y)?(x):(y); u64 mx_=(x)<(y)?(y):(x); (x)=mn_; (y)=mx_; }
#define CE_D(x,y) { u64 mn_=(x)<(y)?(x):(y); u64 mx_=(x)<(y)?(y):(x); (x)=mx_; (y)=mn_; }

// LDS-free ballot tournament over NAMED scalars K0..K15 (r28/r30-proven).
#define TOURNEY16(out16, lane) {                                   \
    u64 cur = K0;                                                  \
    for (int r_=0;r_<KNN;r_++){                                    \
      u64 k_ = cur;                                                \
      _Pragma("unroll")                                            \
      for (int o_=32;o_>0;o_>>=1){                                 \
        u64 ok_ = __shfl_xor(k_, o_, 64);                          \
        if (ok_ < k_) k_ = ok_;                                    \
      }                                                            \
      u64 ball_ = __ballot(cur == k_);                             \
      int who_ = __ffsll(ball_) - 1;                               \
      if ((lane) == r_) out16 = k_;                                \
      if ((lane) == who_){                                         \
        K0=K1; K1=K2; K2=K3; K3=K4; K4=K5; K5=K6; K6=K7; K7=K8;    \
        K8=K9; K9=K10; K10=K11; K11=K12; K12=K13; K13=K14;         \
        K14=K15; K15=~0ULL;                                        \
        cur = K0;                                                  \
      }                                                            \
    }                                                              \
  }

// ---------------- dtype detection (proven: picks f32 here) ----------------
__global__ __launch_bounds__(256) void detect_kernel_r34(
    const unsigned* __restrict__ a, int na,
    const unsigned* __restrict__ b, int nb, int* __restrict__ flag)
{
  __shared__ int cnt;
  if (threadIdx.x == 0) cnt = 0;
  __syncthreads();
  int c = 0;
  for (int i = threadIdx.x; i < na; i += 256){
    int ex = (a[i] >> 7) & 0xFF;
    c += (ex >= 113 && ex <= 131) ? 1 : 0;
  }
  for (int i = threadIdx.x; i < nb; i += 256){
    int ex = (b[i] >> 7) & 0xFF;
    c += (ex >= 113 && ex <= 131) ? 1 : 0;
  }
  atomicAdd(&cnt, c);
  __syncthreads();
  if (threadIdx.x == 0) *flag = (cnt > (na + nb) / 2) ? 1 : 0;
}

// ---------------- decode all inputs (fused weight hi/lo split) ----------------
// r34: weight segs (wofs>=0) are split to bf16 hi/lo IN decode (same math the
// old wconv applied to the same value -> bit-identical) — deletes the wconv
// dispatch and its 11MB f32 round-trip. seg 0 (feats) -> fh/fl as before;
// other segs -> f32.
struct SegTable {
  const void* src[16];
  float*      dst[16];
  int         cnt[16];
  int         wofs[16];   // >=0: offset into wh/wl for weight segs, else -1
  int         total;
};

__global__ __launch_bounds__(256) void decode_kernel_r34(SegTable t,
    unsigned short* __restrict__ fh, unsigned short* __restrict__ fl,
    unsigned short* __restrict__ dh, unsigned short* __restrict__ dl,
    const int* __restrict__ flag)
{
  const int is_bf16 = *flag;
  for (int e = blockIdx.x*256 + threadIdx.x; e < t.total; e += gridDim.x*256){
    int rem = e, s = 0;
    while (rem >= t.cnt[s]){ rem -= t.cnt[s]; ++s; }
    float v;
    if (is_bf16) v = __uint_as_float(((unsigned)((const unsigned short*)t.src[s])[rem]) << 16);
    else         v = ((const float*)t.src[s])[rem];
    if (s == 0){
      unsigned short hb = bf16_rne(v);
      float hf = __uint_as_float(((unsigned)hb) << 16);
      fh[rem] = hb;
      fl[rem] = bf16_rne(v - hf);
    } else {
      int wo = t.wofs[s];
      if (wo >= 0){
        unsigned short hb = bf16_rne(v);
        float hf = __uint_as_float(((unsigned)hb) << 16);
        dh[wo + rem] = hb;
        dl[wo + rem] = bf16_rne(v - hf);
      } else {
        t.dst[s][rem] = v;
      }
    }
  }
}

// ---------------- bucket pre-pass ----------------
__global__ __launch_bounds__(256) void zero_kernel_r34(int* __restrict__ hist, int* __restrict__ cursor,
                                                       int* __restrict__ ocnt)
{
  int t = blockIdx.x*256 + threadIdx.x;
  if (t < NB){ hist[t] = 0; cursor[t] = 0; }
  if (blockIdx.x == 0 && threadIdx.x == 0) *ocnt = 0;
}

__global__ __launch_bounds__(256) void count_kernel_r34(const float* __restrict__ cents,
                                                        int* __restrict__ hist)
{
  int i = blockIdx.x*256 + threadIdx.x;
  if (i < NND) atomicAdd(&hist[bucketof(cents[2*i])], 1);
}

__global__ __launch_bounds__(1024) void scan_kernel_r34(const int* __restrict__ hist,
                                                        int* __restrict__ offs)
{
  __shared__ int s[1024];
  int t = threadIdx.x;
  int h0 = hist[t*4], h1 = hist[t*4+1], h2 = hist[t*4+2], h3 = hist[t*4+3];
  int tot = h0+h1+h2+h3;
  s[t] = tot;
  __syncthreads();
  for (int d=1; d<1024; d<<=1){
    int v = (t >= d) ? s[t-d] : 0;
    __syncthreads();
    s[t] += v;
    __syncthreads();
  }
  int excl = s[t] - tot;
  offs[t*4]   = excl;
  offs[t*4+1] = excl + h0;
  offs[t*4+2] = excl + h0 + h1;
  offs[t*4+3] = excl + h0 + h1 + h2;
}

__global__ __launch_bounds__(256) void scatter_kernel_r34(const float* __restrict__ cents,
    const int* __restrict__ offs, int* __restrict__ cursor,
    float2* __restrict__ sxy, int* __restrict__ sid)
{
  int i = blockIdx.x*256 + threadIdx.x;
  if (i < NND){
    float x = cents[2*i], y = cents[2*i+1];
    int b = bucketof(x);
    int pos = offs[b] + atomicAdd(&cursor[b], 1);
    sxy[pos] = make_float2(x, y);
    sid[pos] = i;
  }
}

// ---------------- FUSED: encoder GEMM (blocks >= KBLK) || knn_fixed (blocks < KBLK) ----------------
// r32-proven (380.5us total; r33's enc-first was neutral-to-worse). Bodies
// byte-identical to standalone forms -> bit-identical.
__global__ __launch_bounds__(256, 4) void fused_enc_knn_r34(
    // encoder args
    const unsigned short* __restrict__ A1h, const unsigned short* __restrict__ A1l,
    const unsigned short* __restrict__ W1h, const unsigned short* __restrict__ W1l,
    const float* __restrict__ bias,
    unsigned short* __restrict__ Ch, unsigned short* __restrict__ Cl,
    // knn args
    const float2* __restrict__ sxy, const int* __restrict__ sid,
    const float* __restrict__ cents, const int* __restrict__ offs,
    int* __restrict__ idx_out, float* __restrict__ w_out,
    int* __restrict__ ocnt, int* __restrict__ olist, float* __restrict__ othr)
{
  __shared__ unsigned short sbW[3][2][2048];   // 24KB, encoder path only
  const int lane = threadIdx.x & 63, wv = threadIdx.x >> 6;

  if (blockIdx.x >= KBLK){
    // ================= encoder body (mm_mfma_r30 <256,false,true,true>) ===========
    constexpr int NW = 2, NA = 2;
    constexpr int NCG = 4, LG = 2;
    constexpr int RTM = (NND + 63) / 64;   // 188
    const int ebid = blockIdx.x - KBLK;
    const int xcd = ebid & 7;
    const int cg  = (ebid >> 3) & (NCG - 1);
    const int rt  = ((ebid >> (3 + LG)) << 3) + xcd;
    if (rt >= RTM) return;
    const int row0 = rt*64;
    const int n0 = cg*64;
    const int l15 = lane & 15;
    const int quad = lane >> 4;

    const size_t woff = (size_t)(n0 + lane) * DM;
    const unsigned short* wsrc = ((wv < 2) ? W1h : W1l) + woff;
    const int wtile = wv >> 1, q0 = (wv & 1) * 2;

    const int am = min(row0 + wv*16 + l15, NND-1);
    const size_t abase = (size_t)am*DM + quad*8;

    f4_t acc[4];
    #pragma unroll
    for (int t=0;t<4;t++) acc[t] = (f4_t){0.f,0.f,0.f,0.f};

    bf8_t A1H[3], A1L[3];

    auto STAGE = [&](int b, int ks){
      #pragma unroll
      for (int j=0;j<2;j++)
        gload16(wsrc + ks*32 + (q0+j)*8, &sbW[b][wtile][(q0+j)*512]);
    };
    auto LOADA = [&](int s, int ks){
      A1H[s] = *(const bf8_t*)(A1h + abase + ks*32);
      A1L[s] = *(const bf8_t*)(A1l + abase + ks*32);
    };

    STAGE(0, 0); LOADA(0, 0);
    STAGE(1, 1); LOADA(1, 1);
    constexpr int NKS = DM/32;             // 8
    #pragma unroll
    for (int ks=0; ks<NKS; ++ks){
      const int b = ks % 3;
      if (ks + 2 < NKS){ STAGE((ks+2)%3, ks+2); LOADA((ks+2)%3, ks+2); }
      if (ks + 2 < NKS)      asm volatile("s_waitcnt vmcnt(%0)" :: "i"(2*(NW+NA)) : "memory");
      else if (ks + 1 < NKS) asm volatile("s_waitcnt vmcnt(%0)" :: "i"(NW+NA) : "memory");
      else                   asm volatile("s_waitcnt vmcnt(0)" ::: "memory");
      __builtin_amdgcn_sched_barrier(0);
      __builtin_amdgcn_s_barrier();
      __builtin_amdgcn_sched_barrier(0);
      {
        bf8_t a1h = A1H[b], a1l = A1L[b];
        #pragma unroll
        for (int t=0;t<4;t++){
          const int wr = quad*512 + (t*16 + l15)*8;
          bf8_t bh = *(const bf8_t*)&sbW[b][0][wr];
          bf8_t bl = *(const bf8_t*)&sbW[b][1][wr];
          acc[t] = __builtin_amdgcn_mfma_f32_16x16x32_bf16(a1h, bh, acc[t], 0, 0, 0);
          acc[t] = __builtin_amdgcn_mfma_f32_16x16x32_bf16(a1h, bl, acc[t], 0, 0, 0);
          acc[t] = __builtin_amdgcn_mfma_f32_16x16x32_bf16(a1l, bh, acc[t], 0, 0, 0);
        }
      }
      __builtin_amdgcn_sched_barrier(0);
      asm volatile("s_waitcnt lgkmcnt(0)" ::: "memory");
      __builtin_amdgcn_s_barrier();
      __builtin_amdgcn_sched_barrier(0);
    }

    #pragma unroll
    for (int t=0;t<4;t++){
      int n = n0 + t*16 + l15;
      float bv = bias[n];
      #pragma unroll
      for (int r=0;r<4;r++){
        int row = row0 + wv*16 + quad*4 + r;
        if (row < NND){
          float v = geluf(acc[t][r] + bv);
          unsigned short hb = bf16_rne(v);
          float hf = __uint_as_float(((unsigned)hb) << 16);
          Ch[(size_t)row*DM + n] = hb;
          Cl[(size_t)row*DM + n] = bf16_rne(v - hf);
        }
      }
    }
    return;
  }

  // ================= knn_fixed body (r30: named-scalar + shift tournament, LDS-free) =====
  const int n = blockIdx.x*4 + wv;
  const float xi = cents[2*n];
  const float yi = cents[2*n+1];
  float sx = xi*xi; FPBAR(sx);
  float sy = yi*yi; FPBAR(sy);
  float sqi = sx + sy; FPBAR(sqi);

  const int start = offs[bucketof(xi)];
  const bool isR = lane < 32;
  const int lo = isR ? lane : (lane - 32);

  u64 K0,K1,K2,K3,K4,K5,K6,K7,K8,K9,K10,K11,K12,K13,K14,K15;
  #define KROUND(r, K) { \
    int myp = isR ? (start + (r)*32 + lo) : (start - 1 - (r)*32 - lo); \
    bool act = (myp >= 0) && (myp < NND); \
    float2 cu = make_float2(0.f, 0.f); \
    int jd = -1; \
    if (act){ cu = sxy[myp]; jd = sid[myp]; } \
    u64 key = make_key(xi, yi, sqi, cu.x, cu.y, jd, n); \
    K = act ? key : ~0ULL; }
  KROUND(0,K0)   KROUND(1,K1)   KROUND(2,K2)   KROUND(3,K3)
  KROUND(4,K4)   KROUND(5,K5)   KROUND(6,K6)   KROUND(7,K7)
  KROUND(8,K8)   KROUND(9,K9)   KROUND(10,K10) KROUND(11,K11)
  KROUND(12,K12) KROUND(13,K13) KROUND(14,K14) KROUND(15,K15)
  #undef KROUND

  // bitonic sort network, 16 keys ascending (80 compare-exchanges, static)
  CE_A(K0,K1)  CE_D(K2,K3)  CE_A(K4,K5)  CE_D(K6,K7)
  CE_A(K8,K9)  CE_D(K10,K11) CE_A(K12,K13) CE_D(K14,K15)
  CE_A(K0,K2)  CE_A(K1,K3)  CE_D(K4,K6)  CE_D(K5,K7)
  CE_A(K8,K10) CE_A(K9,K11) CE_D(K12,K14) CE_D(K13,K15)
  CE_A(K0,K1)  CE_A(K2,K3)  CE_D(K4,K5)  CE_D(K6,K7)
  CE_A(K8,K9)  CE_A(K10,K11) CE_D(K12,K13) CE_D(K14,K15)
  CE_A(K0,K4)  CE_A(K1,K5)  CE_A(K2,K6)  CE_A(K3,K7)
  CE_D(K8,K12) CE_D(K9,K13) CE_D(K10,K14) CE_D(K11,K15)
  CE_A(K0,K2)  CE_A(K1,K3)  CE_A(K4,K6)  CE_A(K5,K7)
  CE_D(K8,K10) CE_D(K9,K11) CE_D(K12,K14) CE_D(K13,K15)
  CE_A(K0,K1)  CE_A(K2,K3)  CE_A(K4,K5)  CE_A(K6,K7)
  CE_D(K8,K9)  CE_D(K10,K11) CE_D(K12,K13) CE_D(K14,K15)
  CE_A(K0,K8)  CE_A(K1,K9)  CE_A(K2,K10) CE_A(K3,K11)
  CE_A(K4,K12) CE_A(K5,K13) CE_A(K6,K14) CE_A(K7,K15)
  CE_A(K0,K4)  CE_A(K1,K5)  CE_A(K2,K6)  CE_A(K3,K7)
  CE_A(K8,K12) CE_A(K9,K13) CE_A(K10,K14) CE_A(K11,K15)
  CE_A(K0,K2)  CE_A(K1,K3)  CE_A(K4,K6)  CE_A(K5,K7)
  CE_A(K8,K10) CE_A(K9,K11) CE_A(K12,K14) CE_A(K13,K15)
  CE_A(K0,K1)  CE_A(K2,K3)  CE_A(K4,K5)  CE_A(K6,K7)
  CE_A(K8,K9)  CE_A(K10,K11) CE_A(K12,K13) CE_A(K14,K15)

  u64 out16 = ~0ULL;
  TOURNEY16(out16, lane)

  float B = __uint_as_float((unsigned)(__shfl(out16, KNN-1, 64) >> 32));
  const float thr = B*B + 2e-4f;

  const int qr = min(start + RW*32, NND);
  const int ql = max(start - RW*32, 0);
  bool ok;
  {
    bool rok = (qr >= NND);
    if (!rok){
      float xR = sxy[qr-1].x;
      float dxr = ((float)bucketof(xR)*BW - 8.0f) - xi;
      rok = (dxr > 0.0f) && (dxr*dxr > thr);
    }
    bool lok = (ql <= 0);
    if (!lok){
      float xL = sxy[ql].x;
      float dxl = xi - ((float)(bucketof(xL)+1)*BW - 8.0f);
      lok = (dxl > 0.0f) && (dxl*dxl > thr);
    }
    ok = rok && lok;
  }
  if (lane == 0 && !ok){
    int s = atomicAdd(ocnt, 1);
    olist[s] = n;
    othr[s] = thr;
  }

  write_outputs(out16, lane, n, idx_out, w_out);
}

// ---------------- bounded rescan for deferred nodes ----------------
// r29-proven: array ladder (register-resident) + copy to named scalars +
// inline tournament. Bit-identical outputs.
__global__ __launch_bounds__(256, 4) void knn_ext_r34(
    const float2* __restrict__ sxy, const int* __restrict__ sid,
    const float* __restrict__ cents, const int* __restrict__ offs,
    const int* __restrict__ olist, const float* __restrict__ othr,
    const int* __restrict__ ocnt,
    int* __restrict__ idx_out, float* __restrict__ w_out)
{
  __shared__ u64 merged[64];         // 4 waves x 16 survivors
  const int lane = threadIdx.x & 63, wv = threadIdx.x >> 6;
  const int cnt = *ocnt;

  for (int slot = blockIdx.x; slot < cnt; slot += gridDim.x){
    const int n = olist[slot];
    const float thr = othr[slot];
    const float rB = __fsqrt_rn(thr) * (1.0f + 2e-6f);
    const float xi = cents[2*n];
    const float yi = cents[2*n+1];
    float sx = xi*xi; FPBAR(sx);
    float sy = yi*yi; FPBAR(sy);
    float sqi = sx + sy; FPBAR(sqi);

    const int bL = bucketof(xi - rB);
    const int bR = bucketof(xi + rB);
    const int posL = offs[bL];
    const int posR = (bR + 1 < NB) ? offs[bR + 1] : NND;

    u64 L[KNN];
    #pragma unroll
    for (int t=0;t<KNN;t++) L[t] = ~0ULL;

    int p = posL + (wv<<6) + lane;
    for (; p + 256 < posR; p += 512){
      float2 c0 = sxy[p];       int j0 = sid[p];
      float2 c1 = sxy[p+256];   int j1 = sid[p+256];
      u64 k0 = make_key(xi, yi, sqi, c0.x, c0.y, j0, n);
      u64 k1 = make_key(xi, yi, sqi, c1.x, c1.y, j1, n);
      if (k0 < L[KNN-1]) ladder_insert(L, k0);   // exact: key>=L[15] is a no-op
      if (k1 < L[KNN-1]) ladder_insert(L, k1);
    }
    if (p < posR){
      float2 c0 = sxy[p];
      u64 k0 = make_key(xi, yi, sqi, c0.x, c0.y, sid[p], n);
      if (k0 < L[KNN-1]) ladder_insert(L, k0);
    }

    // copy to named scalars (static) -> spill-proof tournament
    u64 K0=L[0], K1=L[1], K2=L[2],  K3=L[3],  K4=L[4],  K5=L[5],  K6=L[6],  K7=L[7],
        K8=L[8], K9=L[9], K10=L[10],K11=L[11],K12=L[12],K13=L[13],K14=L[14],K15=L[15];
    u64 w16 = ~0ULL;
    TOURNEY16(w16, lane)

    if (lane < KNN) merged[(wv<<4) + lane] = w16;
    __syncthreads();
    if (wv == 0){
      u64 out16 = merge64(merged, lane);
      write_outputs(out16, lane, n, idx_out, w_out);
    }
    __syncthreads();   // merged[] reused next slot
  }
}

// ---------------- GEMM: W-in-LDS (depth-2 prefetch) + A-in-registers ----------------
// r30-proven: A per-lane register loads (triple-buffered), W-only LDS with 3
// buffers (depth-2 counted vmcnt), XCD-local swizzle. Unchanged.
template<int OUT, bool DUAL, bool BIAS, bool SPLITOUT>
__global__ __launch_bounds__(256, 4) void mm_mfma_r34(
    const unsigned short* __restrict__ A1h, const unsigned short* __restrict__ A1l,
    const unsigned short* __restrict__ A2h, const unsigned short* __restrict__ A2l,
    const unsigned short* __restrict__ W1h, const unsigned short* __restrict__ W1l,
    const unsigned short* __restrict__ W2h, const unsigned short* __restrict__ W2l,
    const float* __restrict__ bias,
    float* __restrict__ Cf, unsigned short* __restrict__ Ch, unsigned short* __restrict__ Cl)
{
  constexpr int NTILW = DUAL ? 4 : 2;      // W tiles per k-step
  constexpr int NW  = DUAL ? 4 : 2;        // W gload_lds per wave per step
  constexpr int NA  = DUAL ? 4 : 2;        // A register loads per lane per step
  constexpr int NCG = OUT / 64;            // 4 or 2
  constexpr int LG  = (NCG == 4) ? 2 : 1;
  constexpr int RTM = (NND + 63) / 64;     // 188
  __shared__ unsigned short sbW[3][NTILW][2048];   // 3 buffers x W tiles x 4KB
  const int lane = threadIdx.x & 63, wv = threadIdx.x >> 6;
  const int bid = blockIdx.x;
  const int xcd = bid & 7;
  const int cg  = (bid >> 3) & (NCG - 1);
  const int rt  = ((bid >> (3 + LG)) << 3) + xcd;
  if (rt >= RTM) return;
  const int row0 = rt*64;
  const int n0 = cg*64;
  const int l15 = lane & 15;
  const int quad = lane >> 4;

  // W staging: DUAL -> wave wv stages tile wv (4 gloads, one per quad);
  // non-dual -> wave wv stages tile wv>>1, quads {(wv&1)*2, (wv&1)*2+1}.
  const size_t woff = (size_t)(n0 + lane) * DM;
  const unsigned short* wsrc;
  int wtile, q0;
  if (DUAL){
    wsrc = ((wv==0) ? W1h : (wv==1) ? W1l : (wv==2) ? W2h : W2l) + woff;
    wtile = wv; q0 = 0;
  } else {
    wsrc = ((wv < 2) ? W1h : W1l) + woff;
    wtile = wv >> 1; q0 = (wv & 1) * 2;
  }

  // A direct per-lane source (this lane's MFMA A-fragment row)
  const int am = min(row0 + wv*16 + l15, NND-1);
  const size_t abase = (size_t)am*DM + quad*8;

  f4_t acc[4];
  #pragma unroll
  for (int t=0;t<4;t++) acc[t] = (f4_t){0.f,0.f,0.f,0.f};

  bf8_t A1H[3], A1L[3], A2H[3], A2L[3];

  auto STAGE = [&](int b, int ks){
    if (DUAL){
      #pragma unroll
      for (int j=0;j<4;j++)
        gload16(wsrc + ks*32 + j*8, &sbW[b][wtile][j*512]);
    } else {
      #pragma unroll
      for (int j=0;j<2;j++)
        gload16(wsrc + ks*32 + (q0+j)*8, &sbW[b][wtile][(q0+j)*512]);
    }
  };
  auto LOADA = [&](int s, int ks){
    A1H[s] = *(const bf8_t*)(A1h + abase + ks*32);
    A1L[s] = *(const bf8_t*)(A1l + abase + ks*32);
    if (DUAL){
      A2H[s] = *(const bf8_t*)(A2h + abase + ks*32);
      A2L[s] = *(const bf8_t*)(A2l + abase + ks*32);
    }
  };

  STAGE(0, 0); LOADA(0, 0);
  STAGE(1, 1); LOADA(1, 1);
  constexpr int NKS = DM/32;             // 8
  #pragma unroll
  for (int ks=0; ks<NKS; ++ks){
    const int b = ks % 3;
    if (ks + 2 < NKS){ STAGE((ks+2)%3, ks+2); LOADA((ks+2)%3, ks+2); }
    // wait for step ks's loads: newer = steps ks+1 (and ks+2 if issued)
    if (ks + 2 < NKS)      asm volatile("s_waitcnt vmcnt(%0)" :: "i"(2*(NW+NA)) : "memory");
    else if (ks + 1 < NKS) asm volatile("s_waitcnt vmcnt(%0)" :: "i"(NW+NA) : "memory");
    else                   asm volatile("s_waitcnt vmcnt(0)" ::: "memory");
    __builtin_amdgcn_sched_barrier(0);
    __builtin_amdgcn_s_barrier();        // all waves: W tiles for ks complete
    __builtin_amdgcn_sched_barrier(0);
    {
      bf8_t a1h = A1H[b], a1l = A1L[b];
      bf8_t a2h, a2l;
      if (DUAL){ a2h = A2H[b]; a2l = A2L[b]; }
      #pragma unroll
      for (int t=0;t<4;t++){
        const int wr = quad*512 + (t*16 + l15)*8;
        bf8_t bh = *(const bf8_t*)&sbW[b][0][wr];
        bf8_t bl = *(const bf8_t*)&sbW[b][1][wr];
        acc[t] = __builtin_amdgcn_mfma_f32_16x16x32_bf16(a1h, bh, acc[t], 0, 0, 0);
        acc[t] = __builtin_amdgcn_mfma_f32_16x16x32_bf16(a1h, bl, acc[t], 0, 0, 0);
        acc[t] = __builtin_amdgcn_mfma_f32_16x16x32_bf16(a1l, bh, acc[t], 0, 0, 0);
        if (DUAL){
          bf8_t ch = *(const bf8_t*)&sbW[b][2][wr];
          bf8_t cl = *(const bf8_t*)&sbW[b][3][wr];
          acc[t] = __builtin_amdgcn_mfma_f32_16x16x32_bf16(a2h, ch, acc[t], 0, 0, 0);
          acc[t] = __builtin_amdgcn_mfma_f32_16x16x32_bf16(a2h, cl, acc[t], 0, 0, 0);
          acc[t] = __builtin_amdgcn_mfma_f32_16x16x32_bf16(a2l, ch, acc[t], 0, 0, 0);
        }
      }
    }
    __builtin_amdgcn_sched_barrier(0);
    asm volatile("s_waitcnt lgkmcnt(0)" ::: "memory");
    __builtin_amdgcn_s_barrier();        // all waves done reading buffer b
    __builtin_amdgcn_sched_barrier(0);
  }

  #pragma unroll
  for (int t=0;t<4;t++){
    int n = n0 + t*16 + l15;
    float bv = BIAS ? bias[n] : 0.f;
    #pragma unroll
    for (int r=0;r<4;r++){
      int row = row0 + wv*16 + quad*4 + r;
      if (row < NND){
        float v = geluf(acc[t][r] + bv);
        if (SPLITOUT){
          unsigned short hb = bf16_rne(v);
          float hf = __uint_as_float(((unsigned)hb) << 16);
          Ch[(size_t)row*OUT + n] = hb;
          Cl[(size_t)row*OUT + n] = bf16_rne(v - hf);
        } else {
          Cf[(size_t)row*OUT + n] = v;
        }
      }
    }
  }
}

// ---------------- weighted neighbor aggregation ----------------
__global__ __launch_bounds__(256) void agg_kernel_r34(
    const unsigned short* __restrict__ hh, const unsigned short* __restrict__ hl,
    const int* __restrict__ idx, const float* __restrict__ w,
    unsigned short* __restrict__ oh, unsigned short* __restrict__ ol)
{
  const int lane = threadIdx.x & 63, wid = threadIdx.x >> 6;
  const int n = blockIdx.x*4 + wid;
  const int base = n*KNN;
  const int c = lane*4;
  float4 acc = make_float4(0.f,0.f,0.f,0.f);
  for (int k=0;k<KNN;k++){
    int j = idx[base+k];
    float wk = w[base+k];
    ushort4 vh = *(const ushort4*)(hh + (size_t)j*DM + c);
    ushort4 vl = *(const ushort4*)(hl + (size_t)j*DM + c);
    acc.x = fmaf(wk, bfpair(vh.x, vl.x), acc.x);
    acc.y = fmaf(wk, bfpair(vh.y, vl.y), acc.y);
    acc.z = fmaf(wk, bfpair(vh.z, vl.z), acc.z);
    acc.w = fmaf(wk, bfpair(vh.w, vl.w), acc.w);
  }
  unsigned short h0 = bf16_rne(acc.x); float f0 = __uint_as_float(((unsigned)h0) << 16);
  unsigned short h1 = bf16_rne(acc.y); float f1 = __uint_as_float(((unsigned)h1) << 16);
  unsigned short h2 = bf16_rne(acc.z); float f2 = __uint_as_float(((unsigned)h2) << 16);
  unsigned short h3 = bf16_rne(acc.w); float f3 = __uint_as_float(((unsigned)h3) << 16);
  ushort4 sh = make_ushort4(h0, h1, h2, h3);
  ushort4 sl = make_ushort4(bf16_rne(acc.x - f0), bf16_rne(acc.y - f1),
                            bf16_rne(acc.z - f2), bf16_rne(acc.w - f3));
  *(ushort4*)(oh + (size_t)n*DM + c) = sh;
  *(ushort4*)(ol + (size_t)n*DM + c) = sl;
}

// ---------------- h = h + layernorm(tmp)*g + b  (h stored as bf16 hi/lo) ----------------
__global__ __launch_bounds__(256) void ln_res_kernel_r34(
    unsigned short* __restrict__ hh, unsigned short* __restrict__ hl,
    const float* __restrict__ tmp, const float* __restrict__ g, const float* __restrict__ b)
{
  const int lane = threadIdx.x & 63, wid = threadIdx.x >> 6;
  const int n = blockIdx.x*4 + wid;
  float4 x = *(const float4*)(tmp + (size_t)n*DM + lane*4);
  float s = (x.x + x.y) + (x.z + x.w);
  #pragma unroll
  for (int off=32; off>0; off>>=1) s += __shfl_xor(s, off, 64);
  float mu = s * (1.0f/DM);
  float dx0 = x.x-mu, dx1 = x.y-mu, dx2 = x.z-mu, dx3 = x.w-mu;
  float v = (dx0*dx0 + dx1*dx1) + (dx2*dx2 + dx3*dx3);
  #pragma unroll
  for (int off=32; off>0; off>>=1) v += __shfl_xor(v, off, 64);
  float rs = 1.0f / sqrtf(v * (1.0f/DM) + 1e-5f);
  int c = lane*4;
  float4 gv = *(const float4*)(g + c);
  float4 bv = *(const float4*)(b + c);
  ushort4 vh = *(const ushort4*)(hh + (size_t)n*DM + c);
  ushort4 vl = *(const ushort4*)(hl + (size_t)n*DM + c);
  float o0 = bfpair(vh.x, vl.x) + dx0*rs*gv.x + bv.x;
  float o1 = bfpair(vh.y, vl.y) + dx1*rs*gv.y + bv.y;
  float o2 = bfpair(vh.z, vl.z) + dx2*rs*gv.z + bv.z;
  float o3 = bfpair(vh.w, vl.w) + dx3*rs*gv.w + bv.w;
  unsigned short h0 = bf16_rne(o0); float f0 = __uint_as_float(((unsigned)h0) << 16);
  unsigned short h1 = bf16_rne(o1); float f1 = __uint_as_float(((unsigned)h1) << 16);
  unsigned short h2 = bf16_rne(o2); float f2 = __uint_as_float(((unsigned)h2) << 16);
  unsigned short h3 = bf16_rne(o3); float f3 = __uint_as_float(((unsigned)h3) << 16);
  *(ushort4*)(hh + (size_t)n*DM + c) = make_ushort4(h0, h1, h2, h3);
  *(ushort4*)(hl + (size_t)n*DM + c) = make_ushort4(bf16_rne(o0 - f0), bf16_rne(o1 - f1),
                                                    bf16_rne(o2 - f2), bf16_rne(o3 - f3));
}

// ---------------- final: out[n] = sigmoid(dot(hid[n], w2) + b2), dtype per flag ----------------
__global__ __launch_bounds__(256) void cls2_kernel_r34(const float* __restrict__ hid,
    const float* __restrict__ w2, const float* __restrict__ b2,
    void* __restrict__ out, const int* __restrict__ flag)
{
  const int lane = threadIdx.x & 63, wid = threadIdx.x >> 6;
  const int n = blockIdx.x*4 + wid;
  float a = hid[(size_t)n*128 + lane]      * w2[lane]
          + hid[(size_t)n*128 + 64 + lane] * w2[64+lane];
  #pragma unroll
  for (int off=32; off>0; off>>=1) a += __shfl_xor(a, off, 64);
  if (lane == 0){
    float v = 1.0f / (1.0f + expf(-(a + b2[0])));
    if (*flag) ((__hip_bfloat16*)out)[n] = __float2bfloat16(v);
    else       ((float*)out)[n] = v;
  }
}

extern "C" void kernel_launch(void* const* d_in, const int* in_sizes, int n_in,
                              void* d_out, int out_size, void* d_ws, size_t ws_size,
                              hipStream_t stream)
{
  // ---- workspace layout (~46.5 MB), fully rewritten every call ----
  char* base = (char*)d_ws;
  int*   flag = (int*)base;                                   // 16 B slot
  float* wreg = (float*)(base + 16);
  static const int sizes[16] = {
    NND*256, NND*2, 256*256, 256, 256*256, 256*256, 256, 256,
    256*256, 256*256, 256, 256, 128*256, 128, 128, 1
  };
  float* ptrs[16];
  {
    float* p = wreg;
    for (int i = 2; i < 16; i++){ ptrs[i] = p; p += (sizes[i] + 3) & ~3; }
    ptrs[1] = p;                          // cents  [24,000]
    p += NND*2;
    ptrs[0] = p;                          // feats region  [3,072,000 floats]
  }
  float* F    = ptrs[0];                  // f32 tmp view of feats region
  unsigned short* fh = (unsigned short*)ptrs[0];          // feats hi
  unsigned short* fl = fh + (size_t)NND*DM;               // feats lo
  float* C    = ptrs[1];
  float* hbase = F + (size_t)NND*DM;
  unsigned short* h_hi = (unsigned short*)hbase;
  unsigned short* h_lo = h_hi + (size_t)NND*DM;
  float* abase = hbase + (size_t)NND*DM;
  unsigned short* a_hi = (unsigned short*)abase;
  unsigned short* a_lo = a_hi + (size_t)NND*DM;
  float* hid  = abase + (size_t)NND*DM;
  int*  gidx  = (int*)(hid + (size_t)NND*128);
  float* gw   = (float*)(gidx + (size_t)NND*KNN);
  // knn pre-pass scratch
  float2* sxy   = (float2*)(gw + (size_t)NND*KNN);
  int*    sid   = (int*)(sxy + NND);
  int*    hist  = sid + NND;
  int*    cursor= hist + NB;
  int*    offs  = cursor + NB;
  int*    ocnt  = offs + NB;
  int*    olist = ocnt + 4;               // 16B pad keeps wh 16B-aligned
  float*  othr  = (float*)(olist + NND);  // thr per deferred node
  // bf16 hi/lo weights (enc_w | g1_ws | g1_wn | g2_ws | g2_wn | cls_w1), 16B-aligned
  unsigned short* wh = (unsigned short*)(((uintptr_t)(othr + NND) + 15) & ~(uintptr_t)15);
  unsigned short* wl = wh + NWELEM;

  // ---- dtype detect + decode (weights split to hi/lo IN decode; wconv deleted) ----
  detect_kernel_r34<<<1, 256, 0, stream>>>((const unsigned*)d_in[1], 4096,
                                           (const unsigned*)d_in[0], 16384, flag);
  SegTable t;
  int total = 0;
  for (int i = 0; i < 16; i++){
    t.src[i] = d_in[i];
    t.dst[i] = ptrs[i];
    t.cnt[i] = sizes[i];
    t.wofs[i] = -1;
    total += sizes[i];
  }
  t.dst[0] = nullptr;       // feats handled via fh/fl
  t.wofs[2]  = 0;           // enc_w
  t.wofs[4]  = 65536;       // g1_ws
  t.wofs[5]  = 131072;      // g1_wn
  t.wofs[8]  = 196608;      // g2_ws
  t.wofs[9]  = 262144;      // g2_wn
  t.wofs[12] = 327680;      // cls_w1
  t.total = total;
  decode_kernel_r34<<<(total + 255)/256, 256, 0, stream>>>(t, fh, fl, wh, wl, flag);

  const float* enc_b  = ptrs[3];
  const float* g1_g   = ptrs[6];  const float* g1_b   = ptrs[7];
  const float* g2_g   = ptrs[10]; const float* g2_b   = ptrs[11];
  const float* cls_b1 = ptrs[13];
  const float* cls_w2 = ptrs[14]; const float* cls_b2 = ptrs[15];

  dim3 b256(256);
  // knn pre-pass: bucket counting sort by x (+ zero outlier counter)
  zero_kernel_r34<<<(NB + 255)/256, b256, 0, stream>>>(hist, cursor, ocnt);
  count_kernel_r34<<<(NND + 255)/256, b256, 0, stream>>>(C, hist);
  scan_kernel_r34<<<1, 1024, 0, stream>>>(hist, offs);
  scatter_kernel_r34<<<(NND + 255)/256, b256, 0, stream>>>(C, offs, cursor, sxy, sid);
  // swizzled grids: 24 rt-groups of 8 XCD-slots x NCG col-groups
  const int G4 = 24 * 8 * 4;   // 768  (OUT=256)
  const int G2 = 24 * 8 * 2;   // 384  (OUT=128)
  // FUSED: knn_fixed (blocks 0..2999) || encoder GEMM (blocks 3000..3767)
  fused_enc_knn_r34<<<KBLK + G4, b256, 0, stream>>>(
      fh, fl, wh + 0, wl + 0, enc_b, h_hi, h_lo,
      sxy, sid, C, offs, gidx, gw, ocnt, olist, othr);
  knn_ext_r34<<<2048, b256, 0, stream>>>(sxy, sid, C, offs, olist, othr, ocnt, gidx, gw);
  // sage layer 1 (tmp := F region, feats dead after encoder)
  agg_kernel_r34<<<NND/4, b256, 0, stream>>>(h_hi, h_lo, gidx, gw, a_hi, a_lo);
  mm_mfma_r34<256,true,false,false><<<G4, b256, 0, stream>>>(h_hi, h_lo, a_hi, a_lo,
      wh + 65536, wl + 65536, wh + 131072, wl + 131072, nullptr, F, nullptr, nullptr);
  ln_res_kernel_r34<<<NND/4, b256, 0, stream>>>(h_hi, h_lo, F, g1_g, g1_b);
  // sage layer 2
  agg_kernel_r34<<<NND/4, b256, 0, stream>>>(h_hi, h_lo, gidx, gw, a_hi, a_lo);
  mm_mfma_r34<256,true,false,false><<<G4, b256, 0, stream>>>(h_hi, h_lo, a_hi, a_lo,
      wh + 196608, wl + 196608, wh + 262144, wl + 262144, nullptr, F, nullptr, nullptr);
  ln_res_kernel_r34<<<NND/4, b256, 0, stream>>>(h_hi, h_lo, F, g2_g, g2_b);
  // classifier
  mm_mfma_r34<128,false,true,false><<<G2, b256, 0, stream>>>(h_hi, h_lo, nullptr, nullptr,
      wh + 327680, wl + 327680, nullptr, nullptr, cls_b1, hid, nullptr, nullptr);
  cls2_kernel_r34<<<NND/4, b256, 0, stream>>>(hid, cls_w2, cls_b2, d_out, flag);
}